// Round 6
// baseline (406.635 us; speedup 1.0000x reference)
//
#include <hip/hip_runtime.h>

// NaiveCustomLSTM: V block-diagonal (20 blocks of 32), U (nearly) diagonal.
// => 2560 independent 32-wide LSTMs (128 batch x 20 blocks), 512 steps.
//
// R13: R12 structure (2 units/wave, all 4 gates in-lane, weights pinned in
// v96-v223 via asm, LDS h+x broadcast) with the per-step serial chain cut:
// - R11/R12 post-mortem: per-WAVE step time is ~1250 cyc at BOTH 2.5 and
//   1.25 waves/SIMD -> latency/chain-bound, not issue-bound. Busy accounting
//   shows v_exp/v_rcp are ~28-32 cyc busy each on gfx950 wave64 -> the 10
//   trans/step (300 cyc) dominate, 4 of them on the serial c->h chain.
// - Newton-rcp: all 5 v_rcp_f32 replaced by magic-seed (0x7EF0A3D2) + 2
//   Newton iterations (6 VALU ops, rel err ~1.4e-6; d=1+2^a is in [1,2^30],
//   no overflow/denormal hazards). Removes 150 cyc/step of trans busy.
// - Staged lgkm waits: fma groups start after the FIRST b128 h-read returns
//   (lgkmcnt(7)..(0) interleave) instead of a full lgkmcnt(0) drain.
// - v_pk_mul_f32 first-touch for chain-1 accumulators (kills 4 zero-movs);
//   loop counter SALU hoisted off the h->ds_write critical path.

#define TT 512
#define HN 640
#define BN 128

typedef float f2 __attribute__((ext_vector_type(2)));
typedef unsigned int u32x4 __attribute__((ext_vector_type(4)));

__global__ __attribute__((amdgpu_flat_work_group_size(64, 64)))
void lstm_kernel(
    const float* __restrict__ x,
    const float* __restrict__ Ui, const float* __restrict__ Vi, const float* __restrict__ bi,
    const float* __restrict__ Uf, const float* __restrict__ Vf, const float* __restrict__ bf,
    const float* __restrict__ Uc, const float* __restrict__ Vc, const float* __restrict__ bc,
    const float* __restrict__ Uo, const float* __restrict__ Vo, const float* __restrict__ bo,
    float* __restrict__ out) {
  // LDS layout (bytes): [0..16895] weights: 32 cols x 528B (132 floats; 4
  // floats per k: {Bs*Vi, Bs*Vf, Bg*Vc, Bs*Vo}[k]; 528 stride avoids 32-way
  // bank conflict on the prologue b128 reads). [16896..17151] h (64 floats:
  // lanes 0-31 = batch b0, 32-63 = b1). [17152..18175] x stage: 4 x 64
  // floats {x1b0, x2b0, x1b1, x2b1} for the current 64-step chunk.
  __shared__ __align__(16) float lds[4544];

  const int unit = blockIdx.x;   // 0..1279
  const int lane = threadIdx.x;  // 0..63
  const int j  = unit >> 6;      // hidden block 0..19
  const int bp = unit & 63;      // batch pair
  const int gp = lane >> 5;      // 0: batch 2bp ; 1: batch 2bp+1
  const int n  = lane & 31;
  const int col = j * 32 + n;
  const int b  = bp * 2 + gp;

  const float LOG2E = 1.44269504088896340736f;
  const float Bs = -LOG2E;        // sigmoid gates (i, f, o)
  const float Bg = -2.f * LOG2E;  // tanh gate (g)

  // Stage pre-scaled V-weight columns in LDS (lanes 0-31; hi lanes dup cols).
  if (lane < 32) {
    for (int k = 0; k < 32; ++k) {
      const int r = (j * 32 + k) * HN + col;
      lds[n * 132 + k * 4 + 0] = Bs * Vi[r];
      lds[n * 132 + k * 4 + 1] = Bs * Vf[r];
      lds[n * 132 + k * 4 + 2] = Bg * Vc[r];
      lds[n * 132 + k * 4 + 3] = Bs * Vo[r];
    }
  }

  // Effective input weights per gate (U mask structure), features f1, f2i.
  int f1 = 0, f2i = 0;
  if (j < 16) { f1 = f2i = j; if (j == 0) f2i = 1; else if (j == 2) f2i = 3; }
  auto uw = [&](const float* __restrict__ U, float& w1, float& w2) {
    w1 = 0.f; w2 = 0.f;
    if (j < 16) {
      w1 = U[j * HN + col];
      if (j == 0)      { w1 += U[16 * HN + col]; w2 = U[17 * HN + col]; }
      else if (j == 2) { w1 += U[18 * HN + col]; w2 = U[19 * HN + col]; }
    }
  };
  float wi1, wi2, wf1, wf2, wg1, wg2, wo1, wo2;
  uw(Ui, wi1, wi2); uw(Uf, wf1, wf2); uw(Uc, wg1, wg2); uw(Uo, wo1, wo2);
  const f2 w11IF = {Bs * wi1, Bs * wf1}, w21IF = {Bs * wi2, Bs * wf2};
  const f2 w11GO = {Bg * wg1, Bs * wo1}, w21GO = {Bg * wg2, Bs * wo2};
  const f2 bsIF  = {Bs * bi[col], Bs * bf[col]};
  const f2 bsGO  = {Bg * bc[col], Bs * bo[col]};

  // LDS byte addresses (low 32 bits of a shared pointer = LDS offset).
  const unsigned zb    = (unsigned)(unsigned long long)&lds[0];
  const unsigned wrd   = zb + (unsigned)n * 528u;           // weight reads
  const unsigned laddr = zb + 16896u + (unsigned)lane * 4u; // h write
  const unsigned hrd   = zb + 16896u + (unsigned)gp * 128u; // h reads
  const unsigned xw    = zb + 17152u + (unsigned)lane * 4u; // x stage write
  const unsigned xrb   = zb + 17152u + (unsigned)gp * 512u; // x read base

  // SRDs: x (bounds-checked; last-chunk prefetch reads OOB -> returns 0,
  // unused) and out (per-step h stores).
  u32x4 xsrd, osrd;
  { const unsigned long long a = (unsigned long long)x;
    xsrd.x = (unsigned)a; xsrd.y = (unsigned)(a >> 32);
    xsrd.z = (unsigned)(BN * TT * 16 * 4); xsrd.w = 0x00020000u; }
  { const unsigned long long a = (unsigned long long)out;
    osrd.x = (unsigned)a; osrd.y = (unsigned)(a >> 32);
    osrd.z = (unsigned)((BN * TT * HN + 2 * BN * HN) * 4); osrd.w = 0x00020000u; }

  unsigned voff  = (unsigned)((b * TT * HN + col) * 4);
  unsigned xvoff = (unsigned)((((bp * 2) * TT + lane) * 16 + f1) * 4);
  const int sfd  = (f2i - f1) * 4;

  float h = 0.f, c = 0.f;

  asm volatile(
    // ---- prologue: weights LDS->v[96:223]; x chunk-0 loads ----
    "s_waitcnt lgkmcnt(0)\n\t"
    "ds_read_b128 v[96:99],   %[wrd]\n\t"
    "ds_read_b128 v[100:103], %[wrd] offset:16\n\t"
    "ds_read_b128 v[104:107], %[wrd] offset:32\n\t"
    "ds_read_b128 v[108:111], %[wrd] offset:48\n\t"
    "ds_read_b128 v[112:115], %[wrd] offset:64\n\t"
    "ds_read_b128 v[116:119], %[wrd] offset:80\n\t"
    "ds_read_b128 v[120:123], %[wrd] offset:96\n\t"
    "ds_read_b128 v[124:127], %[wrd] offset:112\n\t"
    "ds_read_b128 v[128:131], %[wrd] offset:128\n\t"
    "ds_read_b128 v[132:135], %[wrd] offset:144\n\t"
    "ds_read_b128 v[136:139], %[wrd] offset:160\n\t"
    "ds_read_b128 v[140:143], %[wrd] offset:176\n\t"
    "ds_read_b128 v[144:147], %[wrd] offset:192\n\t"
    "ds_read_b128 v[148:151], %[wrd] offset:208\n\t"
    "ds_read_b128 v[152:155], %[wrd] offset:224\n\t"
    "ds_read_b128 v[156:159], %[wrd] offset:240\n\t"
    "ds_read_b128 v[160:163], %[wrd] offset:256\n\t"
    "ds_read_b128 v[164:167], %[wrd] offset:272\n\t"
    "ds_read_b128 v[168:171], %[wrd] offset:288\n\t"
    "ds_read_b128 v[172:175], %[wrd] offset:304\n\t"
    "ds_read_b128 v[176:179], %[wrd] offset:320\n\t"
    "ds_read_b128 v[180:183], %[wrd] offset:336\n\t"
    "ds_read_b128 v[184:187], %[wrd] offset:352\n\t"
    "ds_read_b128 v[188:191], %[wrd] offset:368\n\t"
    "ds_read_b128 v[192:195], %[wrd] offset:384\n\t"
    "ds_read_b128 v[196:199], %[wrd] offset:400\n\t"
    "ds_read_b128 v[200:203], %[wrd] offset:416\n\t"
    "ds_read_b128 v[204:207], %[wrd] offset:432\n\t"
    "ds_read_b128 v[208:211], %[wrd] offset:448\n\t"
    "ds_read_b128 v[212:215], %[wrd] offset:464\n\t"
    "ds_read_b128 v[216:219], %[wrd] offset:480\n\t"
    "ds_read_b128 v[220:223], %[wrd] offset:496\n\t"
    "s_mov_b32 s22, 0x8000\n\t"
    "s_add_u32 s23, s22, %[sfd]\n\t"
    "buffer_load_dword v36, %[xvoff], %[xsrd], 0 offen\n\t"
    "buffer_load_dword v37, %[xvoff], %[xsrd], %[sfd] offen\n\t"
    "buffer_load_dword v38, %[xvoff], %[xsrd], s22 offen\n\t"
    "buffer_load_dword v39, %[xvoff], %[xsrd], s23 offen\n\t"
    "s_mov_b32 s21, 8\n\t"
    "Lchunk%=:\n\t"
    // stage this chunk's x; prefetch next chunk's
    "s_waitcnt vmcnt(0)\n\t"
    "ds_write_b32 %[xw], v36\n\t"
    "ds_write_b32 %[xw], v37 offset:256\n\t"
    "ds_write_b32 %[xw], v38 offset:512\n\t"
    "ds_write_b32 %[xw], v39 offset:768\n\t"
    "v_add_u32 %[xvoff], 0x1000, %[xvoff]\n\t"
    "buffer_load_dword v36, %[xvoff], %[xsrd], 0 offen\n\t"
    "buffer_load_dword v37, %[xvoff], %[xsrd], %[sfd] offen\n\t"
    "buffer_load_dword v38, %[xvoff], %[xsrd], s22 offen\n\t"
    "buffer_load_dword v39, %[xvoff], %[xsrd], s23 offen\n\t"
    "v_mov_b32 v33, %[xrb]\n\t"
    "s_mov_b32 s20, 64\n\t"
    "Lstep%=:\n\t"
    // h + x broadcast through LDS (same-wave DS ops execute in order)
    "ds_write_b32 %[laddr], %[h]\n\t"
    "ds_read2_b32 v[88:89], v33 offset0:0 offset1:64\n\t"
    "ds_read_b128 v[48:51], %[hrd]\n\t"
    "ds_read_b128 v[52:55], %[hrd] offset:16\n\t"
    "ds_read_b128 v[56:59], %[hrd] offset:32\n\t"
    "ds_read_b128 v[60:63], %[hrd] offset:48\n\t"
    "ds_read_b128 v[64:67], %[hrd] offset:64\n\t"
    "ds_read_b128 v[68:71], %[hrd] offset:80\n\t"
    "ds_read_b128 v[72:75], %[hrd] offset:96\n\t"
    "ds_read_b128 v[76:79], %[hrd] offset:112\n\t"
    "v_add_u32 v33, 4, v33\n\t"
    "s_waitcnt lgkmcnt(8)\n\t"
    // seeds: accIF0 = bsIF + x1*w11IF + x2*w21IF ; accGO0 likewise
    "v_pk_fma_f32 v[40:41], v[88:89], %[w11IF], %[bsIF] op_sel:[0,0,0] op_sel_hi:[0,1,1]\n\t"
    "v_pk_fma_f32 v[44:45], v[88:89], %[w11GO], %[bsGO] op_sel:[0,0,0] op_sel_hi:[0,1,1]\n\t"
    "v_pk_fma_f32 v[40:41], v[88:89], %[w21IF], v[40:41] op_sel:[1,0,0] op_sel_hi:[1,1,1]\n\t"
    "v_pk_fma_f32 v[44:45], v[88:89], %[w21GO], v[44:45] op_sel:[1,0,0] op_sel_hi:[1,1,1]\n\t"
    // 64 MACs: k=0..31, streams {i,f} (v40-43) and {g,o} (v44-47), h[k]
    // broadcast into both halves via op_sel; staged waits: each fma group
    // starts as soon as its b128 h-read has returned (lgkmcnt 7..0).
    "s_waitcnt lgkmcnt(7)\n\t"
    "v_pk_fma_f32 v[40:41], v[96:97],   v[48:49], v[40:41] op_sel:[0,0,0] op_sel_hi:[1,0,1]\n\t"
    "v_pk_fma_f32 v[44:45], v[98:99],   v[48:49], v[44:45] op_sel:[0,0,0] op_sel_hi:[1,0,1]\n\t"
    "v_pk_mul_f32 v[42:43], v[100:101], v[48:49] op_sel:[0,1] op_sel_hi:[1,1]\n\t"
    "v_pk_mul_f32 v[46:47], v[102:103], v[48:49] op_sel:[0,1] op_sel_hi:[1,1]\n\t"
    "v_pk_fma_f32 v[40:41], v[104:105], v[50:51], v[40:41] op_sel:[0,0,0] op_sel_hi:[1,0,1]\n\t"
    "v_pk_fma_f32 v[44:45], v[106:107], v[50:51], v[44:45] op_sel:[0,0,0] op_sel_hi:[1,0,1]\n\t"
    "v_pk_fma_f32 v[42:43], v[108:109], v[50:51], v[42:43] op_sel:[0,1,0] op_sel_hi:[1,1,1]\n\t"
    "v_pk_fma_f32 v[46:47], v[110:111], v[50:51], v[46:47] op_sel:[0,1,0] op_sel_hi:[1,1,1]\n\t"
    "s_waitcnt lgkmcnt(6)\n\t"
    "v_pk_fma_f32 v[40:41], v[112:113], v[52:53], v[40:41] op_sel:[0,0,0] op_sel_hi:[1,0,1]\n\t"
    "v_pk_fma_f32 v[44:45], v[114:115], v[52:53], v[44:45] op_sel:[0,0,0] op_sel_hi:[1,0,1]\n\t"
    "v_pk_fma_f32 v[42:43], v[116:117], v[52:53], v[42:43] op_sel:[0,1,0] op_sel_hi:[1,1,1]\n\t"
    "v_pk_fma_f32 v[46:47], v[118:119], v[52:53], v[46:47] op_sel:[0,1,0] op_sel_hi:[1,1,1]\n\t"
    "v_pk_fma_f32 v[40:41], v[120:121], v[54:55], v[40:41] op_sel:[0,0,0] op_sel_hi:[1,0,1]\n\t"
    "v_pk_fma_f32 v[44:45], v[122:123], v[54:55], v[44:45] op_sel:[0,0,0] op_sel_hi:[1,0,1]\n\t"
    "v_pk_fma_f32 v[42:43], v[124:125], v[54:55], v[42:43] op_sel:[0,1,0] op_sel_hi:[1,1,1]\n\t"
    "v_pk_fma_f32 v[46:47], v[126:127], v[54:55], v[46:47] op_sel:[0,1,0] op_sel_hi:[1,1,1]\n\t"
    "s_waitcnt lgkmcnt(5)\n\t"
    "v_pk_fma_f32 v[40:41], v[128:129], v[56:57], v[40:41] op_sel:[0,0,0] op_sel_hi:[1,0,1]\n\t"
    "v_pk_fma_f32 v[44:45], v[130:131], v[56:57], v[44:45] op_sel:[0,0,0] op_sel_hi:[1,0,1]\n\t"
    "v_pk_fma_f32 v[42:43], v[132:133], v[56:57], v[42:43] op_sel:[0,1,0] op_sel_hi:[1,1,1]\n\t"
    "v_pk_fma_f32 v[46:47], v[134:135], v[56:57], v[46:47] op_sel:[0,1,0] op_sel_hi:[1,1,1]\n\t"
    "v_pk_fma_f32 v[40:41], v[136:137], v[58:59], v[40:41] op_sel:[0,0,0] op_sel_hi:[1,0,1]\n\t"
    "v_pk_fma_f32 v[44:45], v[138:139], v[58:59], v[44:45] op_sel:[0,0,0] op_sel_hi:[1,0,1]\n\t"
    "v_pk_fma_f32 v[42:43], v[140:141], v[58:59], v[42:43] op_sel:[0,1,0] op_sel_hi:[1,1,1]\n\t"
    "v_pk_fma_f32 v[46:47], v[142:143], v[58:59], v[46:47] op_sel:[0,1,0] op_sel_hi:[1,1,1]\n\t"
    "s_waitcnt lgkmcnt(4)\n\t"
    "v_pk_fma_f32 v[40:41], v[144:145], v[60:61], v[40:41] op_sel:[0,0,0] op_sel_hi:[1,0,1]\n\t"
    "v_pk_fma_f32 v[44:45], v[146:147], v[60:61], v[44:45] op_sel:[0,0,0] op_sel_hi:[1,0,1]\n\t"
    "v_pk_fma_f32 v[42:43], v[148:149], v[60:61], v[42:43] op_sel:[0,1,0] op_sel_hi:[1,1,1]\n\t"
    "v_pk_fma_f32 v[46:47], v[150:151], v[60:61], v[46:47] op_sel:[0,1,0] op_sel_hi:[1,1,1]\n\t"
    "v_pk_fma_f32 v[40:41], v[152:153], v[62:63], v[40:41] op_sel:[0,0,0] op_sel_hi:[1,0,1]\n\t"
    "v_pk_fma_f32 v[44:45], v[154:155], v[62:63], v[44:45] op_sel:[0,0,0] op_sel_hi:[1,0,1]\n\t"
    "v_pk_fma_f32 v[42:43], v[156:157], v[62:63], v[42:43] op_sel:[0,1,0] op_sel_hi:[1,1,1]\n\t"
    "v_pk_fma_f32 v[46:47], v[158:159], v[62:63], v[46:47] op_sel:[0,1,0] op_sel_hi:[1,1,1]\n\t"
    "s_waitcnt lgkmcnt(3)\n\t"
    "v_pk_fma_f32 v[40:41], v[160:161], v[64:65], v[40:41] op_sel:[0,0,0] op_sel_hi:[1,0,1]\n\t"
    "v_pk_fma_f32 v[44:45], v[162:163], v[64:65], v[44:45] op_sel:[0,0,0] op_sel_hi:[1,0,1]\n\t"
    "v_pk_fma_f32 v[42:43], v[164:165], v[64:65], v[42:43] op_sel:[0,1,0] op_sel_hi:[1,1,1]\n\t"
    "v_pk_fma_f32 v[46:47], v[166:167], v[64:65], v[46:47] op_sel:[0,1,0] op_sel_hi:[1,1,1]\n\t"
    "v_pk_fma_f32 v[40:41], v[168:169], v[66:67], v[40:41] op_sel:[0,0,0] op_sel_hi:[1,0,1]\n\t"
    "v_pk_fma_f32 v[44:45], v[170:171], v[66:67], v[44:45] op_sel:[0,0,0] op_sel_hi:[1,0,1]\n\t"
    "v_pk_fma_f32 v[42:43], v[172:173], v[66:67], v[42:43] op_sel:[0,1,0] op_sel_hi:[1,1,1]\n\t"
    "v_pk_fma_f32 v[46:47], v[174:175], v[66:67], v[46:47] op_sel:[0,1,0] op_sel_hi:[1,1,1]\n\t"
    "s_waitcnt lgkmcnt(2)\n\t"
    "v_pk_fma_f32 v[40:41], v[176:177], v[68:69], v[40:41] op_sel:[0,0,0] op_sel_hi:[1,0,1]\n\t"
    "v_pk_fma_f32 v[44:45], v[178:179], v[68:69], v[44:45] op_sel:[0,0,0] op_sel_hi:[1,0,1]\n\t"
    "v_pk_fma_f32 v[42:43], v[180:181], v[68:69], v[42:43] op_sel:[0,1,0] op_sel_hi:[1,1,1]\n\t"
    "v_pk_fma_f32 v[46:47], v[182:183], v[68:69], v[46:47] op_sel:[0,1,0] op_sel_hi:[1,1,1]\n\t"
    "v_pk_fma_f32 v[40:41], v[184:185], v[70:71], v[40:41] op_sel:[0,0,0] op_sel_hi:[1,0,1]\n\t"
    "v_pk_fma_f32 v[44:45], v[186:187], v[70:71], v[44:45] op_sel:[0,0,0] op_sel_hi:[1,0,1]\n\t"
    "v_pk_fma_f32 v[42:43], v[188:189], v[70:71], v[42:43] op_sel:[0,1,0] op_sel_hi:[1,1,1]\n\t"
    "v_pk_fma_f32 v[46:47], v[190:191], v[70:71], v[46:47] op_sel:[0,1,0] op_sel_hi:[1,1,1]\n\t"
    "s_waitcnt lgkmcnt(1)\n\t"
    "v_pk_fma_f32 v[40:41], v[192:193], v[72:73], v[40:41] op_sel:[0,0,0] op_sel_hi:[1,0,1]\n\t"
    "v_pk_fma_f32 v[44:45], v[194:195], v[72:73], v[44:45] op_sel:[0,0,0] op_sel_hi:[1,0,1]\n\t"
    "v_pk_fma_f32 v[42:43], v[196:197], v[72:73], v[42:43] op_sel:[0,1,0] op_sel_hi:[1,1,1]\n\t"
    "v_pk_fma_f32 v[46:47], v[198:199], v[72:73], v[46:47] op_sel:[0,1,0] op_sel_hi:[1,1,1]\n\t"
    "v_pk_fma_f32 v[40:41], v[200:201], v[74:75], v[40:41] op_sel:[0,0,0] op_sel_hi:[1,0,1]\n\t"
    "v_pk_fma_f32 v[44:45], v[202:203], v[74:75], v[44:45] op_sel:[0,0,0] op_sel_hi:[1,0,1]\n\t"
    "v_pk_fma_f32 v[42:43], v[204:205], v[74:75], v[42:43] op_sel:[0,1,0] op_sel_hi:[1,1,1]\n\t"
    "v_pk_fma_f32 v[46:47], v[206:207], v[74:75], v[46:47] op_sel:[0,1,0] op_sel_hi:[1,1,1]\n\t"
    "s_waitcnt lgkmcnt(0)\n\t"
    "v_pk_fma_f32 v[40:41], v[208:209], v[76:77], v[40:41] op_sel:[0,0,0] op_sel_hi:[1,0,1]\n\t"
    "v_pk_fma_f32 v[44:45], v[210:211], v[76:77], v[44:45] op_sel:[0,0,0] op_sel_hi:[1,0,1]\n\t"
    "v_pk_fma_f32 v[42:43], v[212:213], v[76:77], v[42:43] op_sel:[0,1,0] op_sel_hi:[1,1,1]\n\t"
    "v_pk_fma_f32 v[46:47], v[214:215], v[76:77], v[46:47] op_sel:[0,1,0] op_sel_hi:[1,1,1]\n\t"
    "v_pk_fma_f32 v[40:41], v[216:217], v[78:79], v[40:41] op_sel:[0,0,0] op_sel_hi:[1,0,1]\n\t"
    "v_pk_fma_f32 v[44:45], v[218:219], v[78:79], v[44:45] op_sel:[0,0,0] op_sel_hi:[1,0,1]\n\t"
    "v_pk_fma_f32 v[42:43], v[220:221], v[78:79], v[42:43] op_sel:[0,1,0] op_sel_hi:[1,1,1]\n\t"
    "v_pk_fma_f32 v[46:47], v[222:223], v[78:79], v[46:47] op_sel:[0,1,0] op_sel_hi:[1,1,1]\n\t"
    // reduce: aI=v40 aF=v41 aG=v44 aO=v45 (pre-scaled exp2 args)
    "v_pk_add_f32 v[40:41], v[40:41], v[42:43]\n\t"
    "v_pk_add_f32 v[44:45], v[44:45], v[46:47]\n\t"
    "v_exp_f32 v80, v40\n\t"
    "v_exp_f32 v81, v41\n\t"
    "v_exp_f32 v82, v44\n\t"
    "v_exp_f32 v83, v45\n\t"
    "s_sub_u32 s20, s20, 1\n\t"       // loop SALU hoisted off the h chain
    "s_cmp_lg_u32 s20, 0\n\t"
    // d = 1 + 2^a ; sigmoid = 1/d via magic-seed Newton (2 iters, ~1e-6 rel)
    "v_add_f32 v80, 1.0, v80\n\t"
    "v_add_f32 v81, 1.0, v81\n\t"
    "v_add_f32 v82, 1.0, v82\n\t"
    "v_add_f32 v83, 1.0, v83\n\t"
    "v_sub_u32 v84, 0x7ef0a3d2, v80\n\t"
    "v_sub_u32 v85, 0x7ef0a3d2, v81\n\t"
    "v_sub_u32 v86, 0x7ef0a3d2, v82\n\t"
    "v_sub_u32 v87, 0x7ef0a3d2, v83\n\t"
    "v_fma_f32 v90, -v80, v84, 2.0\n\t"
    "v_fma_f32 v91, -v81, v85, 2.0\n\t"
    "v_fma_f32 v92, -v82, v86, 2.0\n\t"
    "v_fma_f32 v93, -v83, v87, 2.0\n\t"
    "v_mul_f32 v84, v84, v90\n\t"
    "v_mul_f32 v85, v85, v91\n\t"
    "v_mul_f32 v86, v86, v92\n\t"
    "v_mul_f32 v87, v87, v93\n\t"
    "v_fma_f32 v90, -v80, v84, 2.0\n\t"
    "v_fma_f32 v91, -v81, v85, 2.0\n\t"
    "v_fma_f32 v92, -v82, v86, 2.0\n\t"
    "v_fma_f32 v93, -v83, v87, 2.0\n\t"
    "v_mul_f32 v84, v84, v90\n\t"         // sig(i)
    "v_mul_f32 v85, v85, v91\n\t"         // sig(f)
    "v_mul_f32 v86, v86, v92\n\t"         // -> tanh(g)
    "v_mul_f32 v87, v87, v93\n\t"         // sig(o)
    "v_fma_f32 v86, 2.0, v86, -1.0\n\t"   // tanh(g)
    "v_mul_f32 v94, v84, v86\n\t"         // sig(i)*tanh(g)
    "v_fma_f32 %[c], v85, %[c], v94\n\t"  // c = sig(f)*c + sig(i)*tanh(g)
    "v_mul_f32 v94, 0xc038aa3b, %[c]\n\t" // -2*log2e * c
    "v_exp_f32 v94, v94\n\t"
    "s_nop 1\n\t"
    "v_add_f32 v94, 1.0, v94\n\t"
    "v_sub_u32 v95, 0x7ef0a3d2, v94\n\t"
    "v_fma_f32 v90, -v94, v95, 2.0\n\t"
    "v_mul_f32 v95, v95, v90\n\t"
    "v_fma_f32 v90, -v94, v95, 2.0\n\t"
    "v_mul_f32 v95, v95, v90\n\t"
    "v_fma_f32 v95, 2.0, v95, -1.0\n\t"   // tanh(c)
    "v_mul_f32 %[h], v87, v95\n\t"        // h = sig(o)*tanh(c)
    "buffer_store_dword %[h], %[voff], %[osrd], 0 offen\n\t"
    "v_add_u32 %[voff], 0xa00, %[voff]\n\t"
    "s_cbranch_scc1 Lstep%=\n\t"
    "s_sub_u32 s21, s21, 1\n\t"
    "s_cmp_lg_u32 s21, 0\n\t"
    "s_cbranch_scc1 Lchunk%=\n\t"
    : [h]"+v"(h), [c]"+v"(c), [voff]"+v"(voff), [xvoff]"+v"(xvoff)
    : [laddr]"v"(laddr), [hrd]"v"(hrd), [xw]"v"(xw), [xrb]"v"(xrb),
      [wrd]"v"(wrd),
      [w11IF]"v"(w11IF), [w21IF]"v"(w21IF), [bsIF]"v"(bsIF),
      [w11GO]"v"(w11GO), [w21GO]"v"(w21GO), [bsGO]"v"(bsGO),
      [xsrd]"s"(xsrd), [osrd]"s"(osrd), [sfd]"s"(sfd)
    : "memory", "scc", "s20", "s21", "s22", "s23",
      "v33","v36","v37","v38","v39",
      "v40","v41","v42","v43","v44","v45","v46","v47",
      "v48","v49","v50","v51","v52","v53","v54","v55",
      "v56","v57","v58","v59","v60","v61","v62","v63",
      "v64","v65","v66","v67","v68","v69","v70","v71",
      "v72","v73","v74","v75","v76","v77","v78","v79",
      "v80","v81","v82","v83","v84","v85","v86","v87",
      "v88","v89","v90","v91","v92","v93","v94","v95",
      "v96","v97","v98","v99","v100","v101","v102","v103",
      "v104","v105","v106","v107","v108","v109","v110","v111",
      "v112","v113","v114","v115","v116","v117","v118","v119",
      "v120","v121","v122","v123","v124","v125","v126","v127",
      "v128","v129","v130","v131","v132","v133","v134","v135",
      "v136","v137","v138","v139","v140","v141","v142","v143",
      "v144","v145","v146","v147","v148","v149","v150","v151",
      "v152","v153","v154","v155","v156","v157","v158","v159",
      "v160","v161","v162","v163","v164","v165","v166","v167",
      "v168","v169","v170","v171","v172","v173","v174","v175",
      "v176","v177","v178","v179","v180","v181","v182","v183",
      "v184","v185","v186","v187","v188","v189","v190","v191",
      "v192","v193","v194","v195","v196","v197","v198","v199",
      "v200","v201","v202","v203","v204","v205","v206","v207",
      "v208","v209","v210","v211","v212","v213","v214","v215",
      "v216","v217","v218","v219","v220","v221","v222","v223");

  out[BN * TT * HN + b * HN + col] = h;             // h_t
  out[BN * TT * HN + BN * HN + b * HN + col] = c;   // c_t
}

extern "C" void kernel_launch(void* const* d_in, const int* in_sizes, int n_in,
                              void* d_out, int out_size, void* d_ws, size_t ws_size,
                              hipStream_t stream) {
  (void)in_sizes; (void)n_in; (void)d_ws; (void)ws_size; (void)out_size;
  const float* x  = (const float*)d_in[0];
  const float* Ui = (const float*)d_in[1];
  const float* Vi = (const float*)d_in[2];
  const float* bi = (const float*)d_in[3];
  const float* Uf = (const float*)d_in[4];
  const float* Vf = (const float*)d_in[5];
  const float* bf = (const float*)d_in[6];
  const float* Uc = (const float*)d_in[7];
  const float* Vc = (const float*)d_in[8];
  const float* bc = (const float*)d_in[9];
  const float* Uo = (const float*)d_in[10];
  const float* Vo = (const float*)d_in[11];
  const float* bo = (const float*)d_in[12];
  float* out = (float*)d_out;

  dim3 grid(1280);  // 20 blocks x 64 batch-pairs; 2 units per wave
  dim3 block(64);
  hipLaunchKernelGGL(lstm_kernel, grid, block, 0, stream,
                     x, Ui, Vi, bi, Uf, Vf, bf, Uc, Vc, bc, Uo, Vo, bo, out);
}